// Round 4
// baseline (222.142 us; speedup 1.0000x reference)
//
#include <hip/hip_runtime.h>
#include <math.h>

#define B_SZ 4096
#define N_PTS 2048
#define BLOCK 256

__device__ __forceinline__ float huber1(float a) {
    // a >= 0, delta = 1: 0.5*q*q + (a - q), q = min(a,1)
    float q = fminf(a, 1.0f);
    return 0.5f * q * q + (a - q);
}

// -------- Stage 1: pure streaming partial sums, 2 blocks per element --------
// even block (role 0): pc rows 0/1 -> s_pp, s_pp2, s_t, s_t2  -> ws_pc[b] (float4)
// odd  block (role 1): x_delta     -> s_d2                    -> ws_d[b]
__global__ __launch_bounds__(BLOCK) void loss_stage1(
    const float* __restrict__ point_cloud,      // (B,3,N)
    const float* __restrict__ x_delta,          // (B,3,N)
    const float* __restrict__ center_label,     // (B,3)
    float4* __restrict__ ws_pc,                 // (B,)
    float*  __restrict__ ws_d)                  // (B,)
{
    const int b    = blockIdx.x >> 1;
    const int role = blockIdx.x & 1;
    const int tid  = threadIdx.x;
    const int wave = tid >> 6;
    const int lane = tid & 63;

    const size_t base = (size_t)b * 3 * N_PTS;

    __shared__ float red[BLOCK / 64][4];

    if (role == 0) {
        // block-uniform scalars (scalar-path loads, overlap with vector loads)
        const float cx = center_label[b * 3 + 0];
        const float cy = center_label[b * 3 + 1];
        const float vnorm  = sqrtf(cx * cx + cy * cy);
        const float pdx = -cy / vnorm;
        const float pdy =  cx / vnorm;

        const float4* px4 = (const float4*)(point_cloud + base);         // row 0
        const float4* py4 = (const float4*)(point_cloud + base + N_PTS); // row 1

        // issue all 4 loads upfront (max MLP)
        const float4 x0 = px4[tid];
        const float4 x1 = px4[tid + BLOCK];
        const float4 y0 = py4[tid];
        const float4 y1 = py4[tid + BLOCK];

        float s_pp = 0.f, s_pp2 = 0.f, s_t = 0.f, s_t2 = 0.f;
        const float xs[8] = {x0.x, x0.y, x0.z, x0.w, x1.x, x1.y, x1.z, x1.w};
        const float ys[8] = {y0.x, y0.y, y0.z, y0.w, y1.x, y1.y, y1.z, y1.w};
        #pragma unroll
        for (int j = 0; j < 8; ++j) {
            const float pp = xs[j] * pdx + ys[j] * pdy;
            const float t  = xs[j] * cx  + ys[j] * cy;
            s_pp += pp; s_pp2 += pp * pp; s_t += t; s_t2 += t * t;
        }

        #pragma unroll
        for (int off = 32; off > 0; off >>= 1) {
            s_pp  += __shfl_down(s_pp,  off, 64);
            s_pp2 += __shfl_down(s_pp2, off, 64);
            s_t   += __shfl_down(s_t,   off, 64);
            s_t2  += __shfl_down(s_t2,  off, 64);
        }
        if (lane == 0) {
            red[wave][0] = s_pp;  red[wave][1] = s_pp2;
            red[wave][2] = s_t;   red[wave][3] = s_t2;
        }
        __syncthreads();
        if (tid == 0) {
            #pragma unroll
            for (int w = 1; w < BLOCK / 64; ++w) {
                s_pp  += red[w][0];
                s_pp2 += red[w][1];
                s_t   += red[w][2];
                s_t2  += red[w][3];
            }
            ws_pc[b] = make_float4(s_pp, s_pp2, s_t, s_t2);
        }
    } else {
        const float4* pd4 = (const float4*)(x_delta + base);  // 1536 float4

        // issue all 6 loads upfront
        float4 d[6];
        #pragma unroll
        for (int k = 0; k < 6; ++k) d[k] = pd4[tid + k * BLOCK];

        // 4 parallel accumulator chains
        float a0 = 0.f, a1 = 0.f, a2 = 0.f, a3 = 0.f;
        #pragma unroll
        for (int k = 0; k < 6; ++k) {
            a0 += d[k].x * d[k].x;
            a1 += d[k].y * d[k].y;
            a2 += d[k].z * d[k].z;
            a3 += d[k].w * d[k].w;
        }
        float s_d2 = (a0 + a1) + (a2 + a3);

        #pragma unroll
        for (int off = 32; off > 0; off >>= 1)
            s_d2 += __shfl_down(s_d2, off, 64);

        if (lane == 0) red[wave][0] = s_d2;
        __syncthreads();
        if (tid == 0) {
            #pragma unroll
            for (int w = 1; w < BLOCK / 64; ++w) s_d2 += red[w][0];
            ws_d[b] = s_d2;
        }
    }
}

// -------- Stage 2: per-element epilogue, one thread per element --------
__global__ __launch_bounds__(BLOCK) void loss_stage2(
    const float4* __restrict__ ws_pc,           // (B,)
    const float*  __restrict__ ws_d,            // (B,)
    const float* __restrict__ mask_xyz_mean,    // (B,3)
    const float* __restrict__ center_label,     // (B,3)
    const float* __restrict__ size_residual,    // (B,3)
    const float* __restrict__ heading_residual, // (B,)
    const float* __restrict__ mean_sizes,       // (8,3)
    const int*   __restrict__ size_class,       // (B,)
    const int*   __restrict__ heading_class,    // (B,)
    float* __restrict__ ws_p)                   // (gridDim.x) partials
{
    const int tid = threadIdx.x;
    const int b   = blockIdx.x * BLOCK + tid;   // grid covers exactly B_SZ

    const float4 pcs = ws_pc[b];
    const float s_pp = pcs.x, s_pp2 = pcs.y, s_t = pcs.z, s_t2 = pcs.w;
    const float s_d2 = ws_d[b];

    const float cx = center_label[b * 3 + 0];
    const float cy = center_label[b * 3 + 1];
    const float cz = center_label[b * 3 + 2];
    const float vnorm2 = cx * cx + cy * cy;
    const float vnorm  = sqrtf(vnorm2);
    const float pdx = -cy / vnorm;
    const float pdy =  cx / vnorm;

    const float mx = mask_xyz_mean[b * 3 + 0];
    const float my = mask_xyz_mean[b * 3 + 1];
    const float mz = mask_xyz_mean[b * 3 + 2];
    const float dxc = mx - cx, dyc = my - cy, dzc = mz - cz;
    const float center_dist = sqrtf(dxc * dxc + dyc * dyc + dzc * dzc);

    const int sc = size_class[b];
    const float l  = mean_sizes[sc * 3 + 0] + size_residual[b * 3 + 0];
    const float w_ = mean_sizes[sc * 3 + 1] + size_residual[b * 3 + 1];
    // h (size z) does not affect the 2D corners used below

    const float theta = heading_residual[b] +
                        (float)heading_class[b] * (float)(M_PI / 12.0);
    const float c = cosf(theta);
    const float s = sinf(theta);
    const float hl = 0.5f * l, hw = 0.5f * w_;

    // bottom corners k=4..7: sx={1,1,-1,-1}, sy={1,-1,-1,1}
    float X[4], Y[4];
    X[0] =  c * hl - s * hw + cx;  Y[0] =  s * hl + c * hw + cy;
    X[1] =  c * hl + s * hw + cx;  Y[1] =  s * hl - c * hw + cy;
    X[2] = -c * hl + s * hw + cx;  Y[2] = -s * hl - c * hw + cy;
    X[3] = -c * hl - s * hw + cx;  Y[3] = -s * hl + c * hw + cy;

    float ppmax = -INFINITY, ppmin = INFINITY;
    float pmax  = -INFINITY, pmin  = INFINITY;
    #pragma unroll
    for (int k = 0; k < 4; ++k) {
        const float pp = X[k] * pdx + Y[k] * pdy;
        const float pj = (X[k] * cx + Y[k] * cy) / vnorm;
        ppmax = fmaxf(ppmax, pp); ppmin = fminf(ppmin, pp);
        pmax  = fmaxf(pmax,  pj); pmin  = fminf(pmin,  pj);
    }
    const float std_y_label  = (ppmax - ppmin) * 0.25f;
    const float mean_y_label = (ppmax + ppmin) * 0.5f;
    const float std_label    = (pmax - pmin) * 0.25f;
    const float mean_label   = (pmax + pmin) * 0.5f;

    const float invN   = 1.0f / (float)N_PTS;
    const float invNm1 = 1.0f / (float)(N_PTS - 1);

    const float mean_y_pc = s_pp * invN;
    const float var_y = (s_pp2 - s_pp * s_pp * invN) * invNm1;
    const float std_y_pc = sqrtf(fmaxf(var_y, 0.0f));

    const float mean_pc = (s_t * invN) / vnorm;
    const float var_x = ((s_t2 - s_t * s_t * invN) * invNm1) / vnorm2;
    const float std_pc = sqrtf(fmaxf(var_x, 0.0f));

    const float delta_norm = sqrtf(s_d2);

    float total =
          0.5f  * huber1(center_dist)
        +         huber1(fabsf(std_label  - std_pc))
        +         huber1(fabsf(mean_label - mean_pc))
        + 0.01f * huber1(delta_norm)
        +         huber1(fabsf(mean_y_label - mean_y_pc))
        +         huber1(fabsf(std_y_label  - std_y_pc));

    // block reduction -> one partial per block
    #pragma unroll
    for (int off = 32; off > 0; off >>= 1)
        total += __shfl_down(total, off, 64);

    __shared__ float red[BLOCK / 64];
    const int wave = tid >> 6;
    const int lane = tid & 63;
    if (lane == 0) red[wave] = total;
    __syncthreads();
    if (tid == 0) {
        #pragma unroll
        for (int w = 1; w < BLOCK / 64; ++w) total += red[w];
        ws_p[blockIdx.x] = total;
    }
}

// -------- Stage 3: 16 partials -> scalar output --------
__global__ void loss_stage3(const float* __restrict__ ws_p, float* __restrict__ out)
{
    const int lane = threadIdx.x;
    float s = (lane < B_SZ / BLOCK) ? ws_p[lane] : 0.0f;
    #pragma unroll
    for (int off = 32; off > 0; off >>= 1)
        s += __shfl_down(s, off, 64);
    if (lane == 0) out[0] = s * (0.4f / (float)B_SZ);
}

extern "C" void kernel_launch(void* const* d_in, const int* in_sizes, int n_in,
                              void* d_out, int out_size, void* d_ws, size_t ws_size,
                              hipStream_t stream) {
    const float* mask_xyz_mean    = (const float*)d_in[0];
    const float* point_cloud      = (const float*)d_in[1];
    const float* x_delta          = (const float*)d_in[2];
    const float* center_label     = (const float*)d_in[3];
    const float* size_residual    = (const float*)d_in[4];
    const float* heading_residual = (const float*)d_in[5];
    const float* mean_sizes       = (const float*)d_in[6];
    const int*   size_class       = (const int*)d_in[7];
    const int*   heading_class    = (const int*)d_in[8];
    float* out = (float*)d_out;

    // workspace layout: 4096 float4 | 4096 float | 16 float  (= 82 KB)
    float4* ws_pc = (float4*)d_ws;
    float*  ws_d  = (float*)d_ws + B_SZ * 4;
    float*  ws_p  = ws_d + B_SZ;

    loss_stage1<<<2 * B_SZ, BLOCK, 0, stream>>>(
        point_cloud, x_delta, center_label, ws_pc, ws_d);
    loss_stage2<<<B_SZ / BLOCK, BLOCK, 0, stream>>>(
        ws_pc, ws_d, mask_xyz_mean, center_label, size_residual,
        heading_residual, mean_sizes, size_class, heading_class, ws_p);
    loss_stage3<<<1, 64, 0, stream>>>(ws_p, out);
}